// Round 1
// 589.136 us; speedup vs baseline: 1.0028x; 1.0028x over previous
//
#include <hip/hip_runtime.h>
#include <stdint.h>

typedef unsigned short u16;
typedef unsigned int u32;
typedef __attribute__((ext_vector_type(8))) short short8;
typedef __attribute__((ext_vector_type(4))) float floatx4;

// B=64, DIM=768, H=12, HEAD=64, SCALE=0.125
// xv: 64x784x768 f32, xa: 64x512x768 f32, xmm: 64x16x768 f32.

__device__ __forceinline__ u16 f2bf_rne(float f) {
  u32 u = __float_as_uint(f);
  return (u16)((u + 0x7fffu + ((u >> 16) & 1u)) >> 16);
}
// pack two f32 bit-patterns -> (bf16(a) | bf16(b)<<16)
__device__ __forceinline__ u32 pack_rne_u(u32 a, u32 b) {
  a += 0x7fffu + ((a >> 16) & 1u);
  b += 0x7fffu + ((b >> 16) & 1u);
  return __builtin_amdgcn_perm(b, a, 0x07060302u);
}

// Raw barrier that does NOT drain vmcnt: outstanding global prefetch loads
// stay in flight across it. lgkmcnt(0) makes this wave's ds_writes visible;
// the empty asm fences the compiler so LDS reads can't hoist above.
__device__ __forceinline__ void block_sync_lds() {
  asm volatile("s_waitcnt lgkmcnt(0)" ::: "memory");
  __builtin_amdgcn_s_barrier();
  asm volatile("" ::: "memory");
}

// ---------------------------------------------------------------------------
// Shared small-GEMM body: C = rowmap(A) @ W (+bias). W 768x768 row-major.
// g_row = (r/rb)*pitch + off + r%rb. 16 rows x 64 cols per block, BK=64.
// ---------------------------------------------------------------------------
__device__ __forceinline__ void sg_body(
    float (*sAt)[20], float (*sW)[64],
    const float* __restrict__ A, int a_pitch, int a_rb, int a_off,
    const float* __restrict__ W, const float* __restrict__ bias,
    float* __restrict__ Cout, int c_pitch, int c_rb, int c_off,
    int rt, int n0)
{
  const int t = threadIdx.x;
  const int g = t >> 6;
  const int c = t & 63;

  float acc[4] = {0.f, 0.f, 0.f, 0.f};

  for (int ks = 0; ks < 12; ++ks) {
    {
      int r = t >> 4;
      int c4 = (t & 15) * 4;
      int lr = rt * 16 + r;
      int grow = (lr / a_rb) * a_pitch + a_off + (lr % a_rb);
      float4 v = *(const float4*)(A + (size_t)grow * 768 + ks * 64 + c4);
      sAt[c4 + 0][r] = v.x;
      sAt[c4 + 1][r] = v.y;
      sAt[c4 + 2][r] = v.z;
      sAt[c4 + 3][r] = v.w;
    }
#pragma unroll
    for (int u = 0; u < 4; ++u) {
      int unit = t + u * 256;
      int r = unit >> 4;
      int c4 = (unit & 15) * 4;
      *(float4*)&sW[r][c4] = *(const float4*)(W + (size_t)(ks * 64 + r) * 768 + n0 + c4);
    }
    __syncthreads();
#pragma unroll 8
    for (int k = 0; k < 64; ++k) {
      float4 a4 = *(const float4*)&sAt[k][g * 4];
      float w = sW[k][c];
      acc[0] += a4.x * w;
      acc[1] += a4.y * w;
      acc[2] += a4.z * w;
      acc[3] += a4.w * w;
    }
    __syncthreads();
  }

  float bs = bias ? bias[n0 + c] : 0.f;
#pragma unroll
  for (int rr = 0; rr < 4; ++rr) {
    int lr = rt * 16 + g * 4 + rr;
    int grow = (lr / c_rb) * c_pitch + c_off + (lr % c_rb);
    Cout[(size_t)grow * 768 + n0 + c] = acc[rr] + bs;
  }
}

// qproj: q_v / q_a / q_f in one launch. grid (64, 12).
__global__ __launch_bounds__(256) void qproj(
    const float* __restrict__ xmm,
    const float* __restrict__ qv_w, const float* __restrict__ qa_w,
    const float* __restrict__ fq_w,
    float* __restrict__ q_v, float* __restrict__ q_a, float* __restrict__ q_f)
{
  __shared__ float sAt[64][20];
  __shared__ float sW[64][64];
  int rt = blockIdx.x;
  int n0 = blockIdx.y * 64;
  if (rt < 16)
    sg_body(sAt, sW, xmm, 16, 4, 8, qv_w, nullptr, q_v, 4, 4, 0, rt, n0);
  else if (rt < 32)
    sg_body(sAt, sW, xmm, 16, 4, 12, qa_w, nullptr, q_a, 4, 4, 0, rt - 16, n0);
  else
    sg_body(sAt, sW, xmm, 16, 8, 0, fq_w, nullptr, q_f, 8, 8, 0, rt - 32, n0);
}

// proj v/a fused. grid (16, 12, 2).
__global__ __launch_bounds__(256) void proj2(
    const float* __restrict__ o_v, const float* __restrict__ o_a,
    const float* __restrict__ projv_w, const float* __restrict__ projv_b,
    const float* __restrict__ proja_w, const float* __restrict__ proja_b,
    float* __restrict__ out0)
{
  __shared__ float sAt[64][20];
  __shared__ float sW[64][64];
  int z = blockIdx.z;
  sg_body(sAt, sW, z ? o_a : o_v, 4, 4, 0,
          z ? proja_w : projv_w, z ? proja_b : projv_b,
          out0, 16, 4, z ? 12 : 8, blockIdx.x, blockIdx.y * 64);
}

// fkv: k1,k2,v1,v2 in one launch. grid (16, 12, 4). dsts contiguous.
__global__ __launch_bounds__(256) void fkv(
    const float* __restrict__ out0,
    const float* __restrict__ fk_w, const float* __restrict__ fv_w,
    float* __restrict__ kbase)
{
  __shared__ float sAt[64][20];
  __shared__ float sW[64][64];
  int z = blockIdx.z;
  const float* W = (z < 2) ? (fk_w + (size_t)(z & 1) * 768 * 768)
                           : (fv_w + (size_t)(z & 1) * 768 * 768);
  int a_off = (z & 1) ? 12 : 8;
  sg_body(sAt, sW, out0, 16, 4, a_off, W, nullptr,
          kbase + (size_t)z * 256 * 768, 4, 4, 0, blockIdx.x, blockIdx.y * 64);
}

// fproj. grid (32, 12).
__global__ __launch_bounds__(256) void fproj(
    const float* __restrict__ o_f,
    const float* __restrict__ fproj_w, const float* __restrict__ fproj_b,
    float* __restrict__ out0)
{
  __shared__ float sAt[64][20];
  __shared__ float sW[64][64];
  sg_body(sAt, sW, o_f, 8, 8, 0, fproj_w, fproj_b, out0, 16, 8, 0,
          blockIdx.x, blockIdx.y * 64);
}

// ---------------------------------------------------------------------------
// qtilde: Qt[b, h*4+qi, d] = sum_e q[b*4+qi, h*64+e] * kvw[d, h*64+e]  (bf16)
// grid (rt=16, nt=12, z=24): z = path*12 + h.
// ---------------------------------------------------------------------------
__global__ __launch_bounds__(256) void qtilde(
    const float* __restrict__ q_v, const float* __restrict__ q_a,
    const float* __restrict__ kvv_w, const float* __restrict__ kva_w,
    u16* __restrict__ Qt_v, u16* __restrict__ Qt_a)
{
  __shared__ float sAt[64][20];
  __shared__ float sW[64][65];

  const int rt = blockIdx.x;
  const int nt = blockIdx.y;
  const int path = blockIdx.z / 12;
  const int h = blockIdx.z % 12;
  const float* q = path ? q_a : q_v;
  const float* kvw = path ? kva_w : kvv_w;
  u16* Qt = path ? Qt_a : Qt_v;

  const int t = threadIdx.x;
  const int g = t >> 6;
  const int c = t & 63;
  const int n0 = nt * 64;

  {
    int r = t >> 4;
    int c4 = (t & 15) * 4;
    float4 v = *(const float4*)(q + (size_t)(rt * 16 + r) * 768 + h * 64 + c4);
    sAt[c4 + 0][r] = v.x;
    sAt[c4 + 1][r] = v.y;
    sAt[c4 + 2][r] = v.z;
    sAt[c4 + 3][r] = v.w;
  }
#pragma unroll
  for (int u = 0; u < 4; ++u) {
    int unit = t + u * 256;
    int d = unit >> 4;
    int c4 = (unit & 15) * 4;
    float4 v = *(const float4*)(kvw + (size_t)(n0 + d) * 1536 + h * 64 + c4);
    sW[d][c4 + 0] = v.x;
    sW[d][c4 + 1] = v.y;
    sW[d][c4 + 2] = v.z;
    sW[d][c4 + 3] = v.w;
  }
  __syncthreads();

  float acc[4] = {0.f, 0.f, 0.f, 0.f};
#pragma unroll 16
  for (int e = 0; e < 64; ++e) {
    float4 a4 = *(const float4*)&sAt[e][g * 4];
    float w = sW[c][e];
    acc[0] += a4.x * w;
    acc[1] += a4.y * w;
    acc[2] += a4.z * w;
    acc[3] += a4.w * w;
  }
#pragma unroll
  for (int rr = 0; rr < 4; ++rr) {
    int rl = rt * 16 + g * 4 + rr;
    Qt[((size_t)(rl >> 2) * 48 + h * 4 + (rl & 3)) * 768 + n0 + c] = f2bf_rne(acc[rr]);
  }
}

// ---------------------------------------------------------------------------
// attn_logits: S[b,i,j] = 0.125 * (Qt_b @ X_b^T)[i,j]. grid (7, 64, 2).
// v2: latency-hiding rewrite.
//  - X staged via ping-pong REGISTER buffers (xA/xB, 8 uint4 each): loads for
//    tile ks+1 issue before pack/write of tile ks -> in flight across the
//    whole compute phase.
//  - LDS X tile double-buffered; raw s_barrier + lgkmcnt(0) only (no vmcnt
//    drain -> prefetch survives the barrier).
//  - Q fragments loaded directly global->VGPR (L2-hot, 16B/lane), no LDS.
// ---------------------------------------------------------------------------
__global__ __launch_bounds__(256) void attn_logits(
    const u16* __restrict__ Qt_v, const u16* __restrict__ Qt_a,
    const float* __restrict__ Xv, const float* __restrict__ Xa,
    float* __restrict__ Sv, float* __restrict__ Sa)
{
  const int z = blockIdx.z;
  const int jt = blockIdx.x;
  if (z == 1 && jt >= 4) return;
  const u16* Qt = z ? Qt_a : Qt_v;
  const float* X = z ? Xa : Xv;
  float* S = z ? Sa : Sv;
  const int N2 = z ? 512 : 784;

  __shared__ __align__(16) u16 sX[2][128 * 64];  // 32 KiB double-buffered

  const int t = threadIdx.x;
  const int lane = t & 63;
  const int wave = t >> 6;
  const int b = blockIdx.y;
  const int j0 = jt * 128;
  const int jmax = (N2 - j0 < 128) ? (N2 - j0) : 128;
  const u16* Qb = Qt + (size_t)b * 48 * 768;
  const float* Xb = X + (size_t)b * N2 * 768;

  const int xr_r = t >> 3;      // X row within tile (+ u*32)
  const int xc = (t & 7) * 8;   // 8-elem column group (floats in G, u16 in LDS)
  const int qrow0 = lane & 15;
  const int qcb = (lane >> 4) * 8;

  floatx4 acc[3][2];
#pragma unroll
  for (int i = 0; i < 3; ++i)
#pragma unroll
    for (int j = 0; j < 2; ++j) acc[i][j] = (floatx4){0.f, 0.f, 0.f, 0.f};

  uint4 xA[4][2], xB[4][2];
  short8 qr[3][2];

#define AL_LOADX(dst, ks_)                                                     \
  do {                                                                         \
    _Pragma("unroll") for (int u = 0; u < 4; ++u) {                            \
      int r_ = xr_r + u * 32;                                                  \
      uint4 a0_ = {0u, 0u, 0u, 0u}, a1_ = {0u, 0u, 0u, 0u};                    \
      if (r_ < jmax) {                                                         \
        const uint4* s_ =                                                      \
            (const uint4*)(Xb + (size_t)(j0 + r_) * 768 + (ks_) * 64 + xc);    \
        a0_ = s_[0];                                                           \
        a1_ = s_[1];                                                           \
      }                                                                        \
      dst[u][0] = a0_;                                                         \
      dst[u][1] = a1_;                                                         \
    }                                                                          \
  } while (0)

#define AL_LOADQ(ks_)                                                          \
  do {                                                                         \
    _Pragma("unroll") for (int i = 0; i < 3; ++i)                              \
      _Pragma("unroll") for (int kk = 0; kk < 2; ++kk)                         \
        qr[i][kk] = *(const short8*)(Qb + (size_t)(i * 16 + qrow0) * 768 +     \
                                     (ks_) * 64 + kk * 32 + qcb);              \
  } while (0)

#define AL_WRITEX(src, bufp)                                                   \
  do {                                                                         \
    _Pragma("unroll") for (int u = 0; u < 4; ++u) {                            \
      int r_ = xr_r + u * 32;                                                  \
      uint4 pk_;                                                               \
      pk_.x = pack_rne_u(src[u][0].x, src[u][0].y);                            \
      pk_.y = pack_rne_u(src[u][0].z, src[u][0].w);                            \
      pk_.z = pack_rne_u(src[u][1].x, src[u][1].y);                            \
      pk_.w = pack_rne_u(src[u][1].z, src[u][1].w);                            \
      *(uint4*)((bufp) + r_ * 64 + (xc ^ ((r_ & 7) * 8))) = pk_;               \
    }                                                                          \
  } while (0)

#define AL_COMPUTE(bufp)                                                       \
  do {                                                                         \
    _Pragma("unroll") for (int kk = 0; kk < 2; ++kk) {                         \
      short8 bfr_[2];                                                          \
      _Pragma("unroll") for (int jj = 0; jj < 2; ++jj) {                       \
        int jr_ = wave * 32 + jj * 16 + qrow0;                                 \
        int kb_ = kk * 32 + qcb;                                               \
        bfr_[jj] =                                                             \
            *(const short8*)((bufp) + jr_ * 64 + (kb_ ^ ((jr_ & 7) * 8)));     \
      }                                                                        \
      _Pragma("unroll") for (int i = 0; i < 3; ++i)                            \
        _Pragma("unroll") for (int jj = 0; jj < 2; ++jj)                       \
          acc[i][jj] = __builtin_amdgcn_mfma_f32_16x16x32_bf16(                \
              qr[i][kk], bfr_[jj], acc[i][jj], 0, 0, 0);                       \
    }                                                                          \
  } while (0)

  u16* sX0 = &sX[0][0];
  u16* sX1 = &sX[1][0];

  AL_LOADX(xA, 0);
  AL_LOADQ(0);
#pragma unroll
  for (int ks = 0; ks < 12; ks += 2) {
    // phase A: consume xA into buf0; prefetch ks+1 into xB first
    AL_LOADX(xB, ks + 1);
    AL_WRITEX(xA, sX0);
    block_sync_lds();
    AL_COMPUTE(sX0);
    AL_LOADQ(ks + 1);
    // phase B: consume xB into buf1; prefetch ks+2 into xA first
    if (ks + 2 < 12) AL_LOADX(xA, ks + 2);
    AL_WRITEX(xB, sX1);
    block_sync_lds();
    AL_COMPUTE(sX1);
    if (ks + 2 < 12) AL_LOADQ(ks + 2);
  }
#undef AL_LOADX
#undef AL_LOADQ
#undef AL_WRITEX
#undef AL_COMPUTE

  const int quad = lane >> 4;
  const int lc = lane & 15;
#pragma unroll
  for (int i = 0; i < 3; ++i)
#pragma unroll
    for (int jj = 0; jj < 2; ++jj) {
      int col = j0 + wave * 32 + jj * 16 + lc;
      if (col < N2) {
        int row0 = i * 16 + quad * 4;
#pragma unroll
        for (int r = 0; r < 4; ++r)
          S[((size_t)b * 48 + row0 + r) * N2 + col] = acc[i][jj][r] * 0.125f;
      }
    }
}

// ---------------------------------------------------------------------------
// softmax_p: P = softmax(S) bf16, zero-padded to N2p. grid (12, 64, 2).
// ---------------------------------------------------------------------------
__global__ __launch_bounds__(256) void softmax_p(
    const float* __restrict__ Sv, const float* __restrict__ Sa,
    u16* __restrict__ Pv, u16* __restrict__ Pa)
{
  const int z = blockIdx.z;
  const float* S = z ? Sa : Sv;
  u16* P = z ? Pa : Pv;
  const int N2 = z ? 512 : 784;
  const int N2p = z ? 512 : 832;

  const int hh = blockIdx.x;
  const int b = blockIdx.y;
  const int t = threadIdx.x;
  const int lane = t & 63;
  const int wave = t >> 6;
  const int row = hh * 4 + wave;
  const float* Srow = S + ((size_t)b * 48 + row) * N2;
  u16* Prow = P + ((size_t)b * 48 + row) * N2p;

  float m = -1e30f;
  for (int j = lane; j < N2; j += 64) m = fmaxf(m, Srow[j]);
#pragma unroll
  for (int off = 32; off > 0; off >>= 1) m = fmaxf(m, __shfl_xor(m, off));

  float e[13];
  float l = 0.f;
  int cnt = 0;
  for (int j = lane; j < N2; j += 64) {
    float p = __expf(Srow[j] - m);
    e[cnt++] = p;
    l += p;
  }
#pragma unroll
  for (int off = 32; off > 0; off >>= 1) l += __shfl_xor(l, off);
  float inv = 1.0f / l;

  cnt = 0;
  for (int j = lane; j < N2; j += 64) Prow[j] = f2bf_rne(e[cnt++] * inv);
  for (int j = N2 + lane; j < N2p; j += 64) Prow[j] = 0;
}

// ---------------------------------------------------------------------------
// attn_px: O[b,i,n] = (P_b @ X_b)[i,n]. grid (6, 64, 2).
// v2: same latency-hiding rewrite as attn_logits.
//  - X staged transposed via ping-pong register buffers, pack to bf16,
//    XOR-swizzled LDS [n][j] layout (rows padded to 72 u16), double-buffered.
//  - P fragments loaded directly global->VGPR (L2-hot, zero-padded rows).
//  - raw s_barrier + lgkmcnt(0) only.
// ---------------------------------------------------------------------------
__global__ __launch_bounds__(256) void attn_px(
    const u16* __restrict__ Pv, const u16* __restrict__ Pa,
    const float* __restrict__ Xv, const float* __restrict__ Xa,
    float* __restrict__ Ov, float* __restrict__ Oa)
{
  const int z = blockIdx.z;
  const u16* P = z ? Pa : Pv;
  const float* X = z ? Xa : Xv;
  float* O = z ? Oa : Ov;
  const int N2 = z ? 512 : 784;
  const int N2p = z ? 512 : 832;

  __shared__ __align__(16) u16 sXT[2][128 * 72];  // 36 KiB double-buffered

  const int t = threadIdx.x;
  const int lane = t & 63;
  const int wave = t >> 6;
  const int nt = blockIdx.x;
  const int b = blockIdx.y;
  const int n0 = nt * 128;
  const u16* Pb = P + (size_t)b * 48 * N2p;
  const float* Xb = X + (size_t)b * N2 * 768;
  const int Ks = N2p >> 6;

  const int jp0 = t >> 5;        // j-pair index (+ u*8)
  const int nq4 = (t & 31) * 4;  // n quad base
  const int qrow0 = lane & 15;
  const int qcb = (lane >> 4) * 8;

  floatx4 acc[3][2];
#pragma unroll
  for (int i = 0; i < 3; ++i)
#pragma unroll
    for (int j = 0; j < 2; ++j) acc[i][j] = (floatx4){0.f, 0.f, 0.f, 0.f};

  uint4 xA[4][2], xB[4][2];
  short8 qr[3][2];

#define PX_LOADX(dst, ks_)                                                     \
  do {                                                                         \
    _Pragma("unroll") for (int u = 0; u < 4; ++u) {                            \
      int j_ = (ks_) * 64 + (jp0 + u * 8) * 2;                                 \
      uint4 a0_ = {0u, 0u, 0u, 0u}, a1_ = {0u, 0u, 0u, 0u};                    \
      if (j_ < N2)                                                             \
        a0_ = *(const uint4*)(Xb + (size_t)j_ * 768 + n0 + nq4);               \
      if (j_ + 1 < N2)                                                         \
        a1_ = *(const uint4*)(Xb + (size_t)(j_ + 1) * 768 + n0 + nq4);         \
      dst[u][0] = a0_;                                                         \
      dst[u][1] = a1_;                                                         \
    }                                                                          \
  } while (0)

#define PX_LOADP(ks_)                                                          \
  do {                                                                         \
    _Pragma("unroll") for (int i = 0; i < 3; ++i)                              \
      _Pragma("unroll") for (int kk = 0; kk < 2; ++kk)                         \
        qr[i][kk] = *(const short8*)(Pb + (size_t)(i * 16 + qrow0) * N2p +     \
                                     (ks_) * 64 + kk * 32 + qcb);              \
  } while (0)

#define PX_WRITEX(src, bufp)                                                   \
  do {                                                                         \
    _Pragma("unroll") for (int u = 0; u < 4; ++u) {                            \
      int jl_ = (jp0 + u * 8) * 2;                                             \
      u32 w0_ = pack_rne_u(src[u][0].x, src[u][1].x);                          \
      u32 w1_ = pack_rne_u(src[u][0].y, src[u][1].y);                          \
      u32 w2_ = pack_rne_u(src[u][0].z, src[u][1].z);                          \
      u32 w3_ = pack_rne_u(src[u][0].w, src[u][1].w);                          \
      _Pragma("unroll") for (int m_ = 0; m_ < 4; ++m_) {                       \
        int n_ = nq4 + m_;                                                     \
        int sw_ = (((n_ >> 2) & 7) ^ ((n_ & 3) << 1)) * 8;                     \
        u32 wv_ = (m_ == 0) ? w0_ : (m_ == 1) ? w1_ : (m_ == 2) ? w2_ : w3_;   \
        *(u32*)((bufp) + n_ * 72 + (jl_ ^ sw_)) = wv_;                         \
      }                                                                        \
    }                                                                          \
  } while (0)

#define PX_COMPUTE(bufp)                                                       \
  do {                                                                         \
    _Pragma("unroll") for (int kk = 0; kk < 2; ++kk) {                         \
      _Pragma("unroll") for (int jj = 0; jj < 2; ++jj) {                       \
        int n_ = wave * 32 + jj * 16 + qrow0;                                  \
        int sw_ = (((n_ >> 2) & 7) ^ ((n_ & 3) << 1)) * 8;                     \
        int kb_ = kk * 32 + qcb;                                               \
        short8 bfr_ = *(const short8*)((bufp) + n_ * 72 + (kb_ ^ sw_));        \
        _Pragma("unroll") for (int i = 0; i < 3; ++i)                          \
          acc[i][jj] = __builtin_amdgcn_mfma_f32_16x16x32_bf16(                \
              qr[i][kk], bfr_, acc[i][jj], 0, 0, 0);                           \
      }                                                                        \
    }                                                                          \
  } while (0)

  u16* sT0 = &sXT[0][0];
  u16* sT1 = &sXT[1][0];

  PX_LOADX(xA, 0);
  PX_LOADP(0);
  int ks = 0;
  for (;;) {
    // phase A: consume xA into buf0
    int more0 = (ks + 1 < Ks);
    if (more0) PX_LOADX(xB, ks + 1);
    PX_WRITEX(xA, sT0);
    block_sync_lds();
    PX_COMPUTE(sT0);
    if (!more0) break;
    PX_LOADP(ks + 1);
    ++ks;
    // phase B: consume xB into buf1
    int more1 = (ks + 1 < Ks);
    if (more1) PX_LOADX(xA, ks + 1);
    PX_WRITEX(xB, sT1);
    block_sync_lds();
    PX_COMPUTE(sT1);
    if (!more1) break;
    PX_LOADP(ks + 1);
    ++ks;
  }
#undef PX_LOADX
#undef PX_LOADP
#undef PX_WRITEX
#undef PX_COMPUTE

  const int quad = lane >> 4;
  const int lc = lane & 15;
#pragma unroll
  for (int i = 0; i < 3; ++i)
#pragma unroll
    for (int jj = 0; jj < 2; ++jj) {
      int col = n0 + wave * 32 + jj * 16 + lc;
      int row0 = i * 16 + quad * 4;
#pragma unroll
      for (int r = 0; r < 4; ++r)
        O[((size_t)b * 48 + row0 + r) * 768 + col] = acc[i][jj][r];
    }
}

// ---------------------------------------------------------------------------
// omix: o[b*4+qi, h*64+e] = sum_d O[b*48+h*4+qi, d] * kvw[d, 768+h*64+e]
// grid (16, 12, 2).
// ---------------------------------------------------------------------------
__global__ __launch_bounds__(256) void omix(
    const float* __restrict__ O_v, const float* __restrict__ O_a,
    const float* __restrict__ kvv_w, const float* __restrict__ kva_w,
    float* __restrict__ o_v, float* __restrict__ o_a)
{
  __shared__ float sAt[64][20];
  __shared__ float sW[64][64];

  const int z = blockIdx.z;
  const float* Ob = z ? O_a : O_v;
  const float* kvw = z ? kva_w : kvv_w;
  float* oo = z ? o_a : o_v;

  const int rt = blockIdx.x;
  const int h = blockIdx.y;
  const int t = threadIdx.x;
  const int g = t >> 6;
  const int c = t & 63;

  float acc[4] = {0.f, 0.f, 0.f, 0.f};

  for (int ks = 0; ks < 12; ++ks) {
    {
      int r = t >> 4;
      int c4 = (t & 15) * 4;
      int rl = rt * 16 + r;
      int arow = (rl >> 2) * 48 + h * 4 + (rl & 3);
      float4 v = *(const float4*)(Ob + (size_t)arow * 768 + ks * 64 + c4);
      sAt[c4 + 0][r] = v.x;
      sAt[c4 + 1][r] = v.y;
      sAt[c4 + 2][r] = v.z;
      sAt[c4 + 3][r] = v.w;
    }
#pragma unroll
    for (int u = 0; u < 4; ++u) {
      int unit = t + u * 256;
      int k = unit >> 4;
      int c4 = (unit & 15) * 4;
      *(float4*)&sW[k][c4] = *(const float4*)(kvw + (size_t)(ks * 64 + k) * 1536 + 768 + h * 64 + c4);
    }
    __syncthreads();
#pragma unroll 8
    for (int k = 0; k < 64; ++k) {
      float4 a4 = *(const float4*)&sAt[k][g * 4];
      float w = sW[k][c];
      acc[0] += a4.x * w;
      acc[1] += a4.y * w;
      acc[2] += a4.z * w;
      acc[3] += a4.w * w;
    }
    __syncthreads();
  }

#pragma unroll
  for (int rr = 0; rr < 4; ++rr) {
    int rl = rt * 16 + g * 4 + rr;
    oo[(size_t)rl * 768 + h * 64 + c] = acc[rr];
  }
}

// ---------------------------------------------------------------------------
// Fusion attention. grid (12, 64).
// ---------------------------------------------------------------------------
__global__ __launch_bounds__(256) void fusion_attn(
    const float* __restrict__ Qf,
    const float* __restrict__ K1, const float* __restrict__ K2,
    const float* __restrict__ V1, const float* __restrict__ V2,
    float* __restrict__ Of,
    float* __restrict__ AttnOut)
{
  const int h = blockIdx.x;
  const int b = blockIdx.y;
  const int t = threadIdx.x;
  const int lane = t & 63;
  const int wave = t >> 6;

  __shared__ float sQ[8][64];
  __shared__ float sK1[4][64], sK2[4][64], sV1[4][64], sV2[4][64];
  __shared__ float sP[8][16];

  for (int idx = t; idx < 512; idx += 256)
    sQ[idx >> 6][idx & 63] = Qf[((size_t)(b * 8 + (idx >> 6))) * 768 + h * 64 + (idx & 63)];
  {
    size_t base = ((size_t)(b * 4 + wave)) * 768 + h * 64 + lane;
    sK1[wave][lane] = K1[base];
    sK2[wave][lane] = K2[base];
    sV1[wave][lane] = V1[base];
    sV2[wave][lane] = V2[base];
  }
  __syncthreads();

  if (t < 128) {
    int qi = t >> 4, m = t & 15, iv = m >> 2, ja = m & 3;
    float s = 0.f;
#pragma unroll
    for (int d = 0; d < 64; ++d) s += sQ[qi][d] * (sK1[iv][d] + sK2[ja][d]);
    s *= 0.125f;
    float mx = s;
#pragma unroll
    for (int off = 8; off > 0; off >>= 1) mx = fmaxf(mx, __shfl_xor(mx, off, 16));
    float p = __expf(s - mx);
    float l = p;
#pragma unroll
    for (int off = 8; off > 0; off >>= 1) l += __shfl_xor(l, off, 16);
    p = p / l;
    sP[qi][m] = p;
    AttnOut[(((size_t)b * 12 + h) * 8 + qi) * 16 + m] = p;
  }
  __syncthreads();

  for (int idx = t; idx < 512; idx += 256) {
    int qi = idx >> 6, d = idx & 63;
    float o = 0.f;
#pragma unroll
    for (int m = 0; m < 16; ++m) o += sP[qi][m] * (sV1[m >> 2][d] + sV2[m & 3][d]);
    Of[((size_t)(b * 8 + qi)) * 768 + h * 64 + d] = o;
  }
}

// ---------------------------------------------------------------------------
extern "C" void kernel_launch(void* const* d_in, const int* in_sizes, int n_in,
                              void* d_out, int out_size, void* d_ws, size_t ws_size,
                              hipStream_t stream)
{
  const float* xmm     = (const float*)d_in[0];
  const float* xv      = (const float*)d_in[1];
  const float* xa      = (const float*)d_in[2];
  const float* qv_w    = (const float*)d_in[3];
  const float* kvv_w   = (const float*)d_in[4];
  const float* projv_w = (const float*)d_in[5];
  const float* projv_b = (const float*)d_in[6];
  const float* qa_w    = (const float*)d_in[7];
  const float* kva_w   = (const float*)d_in[8];
  const float* proja_w = (const float*)d_in[9];
  const float* proja_b = (const float*)d_in[10];
  const float* fq_w    = (const float*)d_in[11];
  const float* fk_w    = (const float*)d_in[12];
  const float* fv_w    = (const float*)d_in[13];
  const float* fproj_w = (const float*)d_in[14];
  const float* fproj_b = (const float*)d_in[15];

  float* out0 = (float*)d_out;                       // 64 x 16 x 768
  float* out1 = out0 + (size_t)64 * 16 * 768;        // 64 x 12 x 8 x 16

  char* ws = (char*)d_ws;
  size_t off = 0;
  float* q_v  = (float*)(ws + off); off += (size_t)256 * 768 * 4;
  float* q_a  = (float*)(ws + off); off += (size_t)256 * 768 * 4;
  float* q_f  = (float*)(ws + off); off += (size_t)512 * 768 * 4;
  u16*   Qt_v = (u16*)(ws + off);   off += (size_t)64 * 48 * 768 * 2;
  u16*   Qt_a = (u16*)(ws + off);   off += (size_t)64 * 48 * 768 * 2;
  float* S_v  = (float*)(ws + off); off += (size_t)64 * 48 * 784 * 4;
  float* S_a  = (float*)(ws + off); off += (size_t)64 * 48 * 512 * 4;
  u16*   P_v  = (u16*)(ws + off);   off += (size_t)64 * 48 * 832 * 2;
  u16*   P_a  = (u16*)(ws + off);   off += (size_t)64 * 48 * 512 * 2;
  float* O_v  = (float*)(ws + off); off += (size_t)64 * 48 * 768 * 4;
  float* O_a  = (float*)(ws + off); off += (size_t)64 * 48 * 768 * 4;
  float* o_v  = (float*)(ws + off); off += (size_t)256 * 768 * 4;
  float* o_a  = (float*)(ws + off); off += (size_t)256 * 768 * 4;
  float* kbase = (float*)(ws + off); off += (size_t)4 * 256 * 768 * 4;  // k1,k2,v1,v2
  float* o_f  = (float*)(ws + off); off += (size_t)512 * 768 * 4;

  float* k1 = kbase;
  float* k2 = kbase + (size_t)256 * 768;
  float* v1 = kbase + (size_t)2 * 256 * 768;
  float* v2 = kbase + (size_t)3 * 256 * 768;

  qproj<<<dim3(64, 12), 256, 0, stream>>>(xmm, qv_w, qa_w, fq_w, q_v, q_a, q_f);
  qtilde<<<dim3(16, 12, 24), 256, 0, stream>>>(q_v, q_a, kvv_w, kva_w, Qt_v, Qt_a);
  attn_logits<<<dim3(7, 64, 2), 256, 0, stream>>>(Qt_v, Qt_a, xv, xa, S_v, S_a);
  softmax_p<<<dim3(12, 64, 2), 256, 0, stream>>>(S_v, S_a, P_v, P_a);
  attn_px<<<dim3(6, 64, 2), 256, 0, stream>>>(P_v, P_a, xv, xa, O_v, O_a);
  omix<<<dim3(16, 12, 2), 256, 0, stream>>>(O_v, O_a, kvv_w, kva_w, o_v, o_a);
  proj2<<<dim3(16, 12, 2), 256, 0, stream>>>(o_v, o_a, projv_w, projv_b, proja_w, proja_b, out0);
  fkv<<<dim3(16, 12, 4), 256, 0, stream>>>(out0, fk_w, fv_w, kbase);
  fusion_attn<<<dim3(12, 64), 256, 0, stream>>>(q_f, k1, k2, v1, v2, o_f, out1);
  fproj<<<dim3(32, 12), 256, 0, stream>>>(o_f, fproj_w, fproj_b, out0);
}